// Round 1
// baseline (11757.634 us; speedup 1.0000x reference)
//
#include <hip/hip_runtime.h>
#include <math.h>

// ---------------------------------------------------------------------------
// VAE_14482629722138 — fp32 correctness-first implementation.
// B=512, T_ENC=T_DEC=64, A=64, ACT_E=64, CF=512, ZD=128, TDIM=520.
// ---------------------------------------------------------------------------

#define B 512
#define TT 64
#define CF 512
#define G4 2048   // 4*CF
#define ZD 128
#define TDIM 520

__device__ __forceinline__ float sigm(float x) { return 1.f / (1.f + expf(-x)); }

// ---------------------------------------------------------------------------
// Generic GEMM: C[M,N] = A[M,K] @ W[N,K]^T (+base) (+bias) (optional relu)
// M = gridDim.y*64 (always 512 here). 64x64 tile, 256 threads, 4x4 microtile.
// gridDim.z>1 -> split-K: block z computes K-chunk and writes slice z of C
// (C + z*M*ldc), no base/bias/relu in that mode.
// ---------------------------------------------------------------------------
__global__ __launch_bounds__(256) void gemm_tn(
    const float* __restrict__ A, int lda,
    const float* __restrict__ W, int ldw,
    int N, int K,
    const float* __restrict__ base,
    const float* __restrict__ bias,
    float* __restrict__ C, int ldc,
    int relu)
{
    __shared__ float As[32][68];
    __shared__ float Ws[32][68];
    const int tid = threadIdx.x;
    const int tx = tid & 15, ty = tid >> 4;
    const int row0 = blockIdx.y << 6;
    const int col0 = blockIdx.x << 6;

    int kbeg = 0, kend = K;
    if (gridDim.z > 1) {
        int kchunk = (K + gridDim.z - 1) / gridDim.z;
        kbeg = blockIdx.z * kchunk;
        kend = kbeg + kchunk; if (kend > K) kend = K;
        C += (size_t)blockIdx.z * (size_t)(gridDim.y << 6) * (size_t)ldc;
    }

    float acc[4][4] = {};

    for (int k0 = kbeg; k0 < kend; k0 += 32) {
        // ---- stage A tile (64 rows x 32 k), transposed to k-major ----
        #pragma unroll
        for (int s = 0; s < 2; ++s) {
            int f = tid + (s << 8);
            int rr = f >> 3;
            int kq = (f & 7) << 2;
            int k = k0 + kq;
            float4 v = make_float4(0.f, 0.f, 0.f, 0.f);
            const float* ap = A + (size_t)(row0 + rr) * (size_t)lda;
            if (k + 3 < kend) {
                v = *(const float4*)(ap + k);
            } else {
                if (k + 0 < kend) v.x = ap[k + 0];
                if (k + 1 < kend) v.y = ap[k + 1];
                if (k + 2 < kend) v.z = ap[k + 2];
                if (k + 3 < kend) v.w = ap[k + 3];
            }
            As[kq + 0][rr] = v.x; As[kq + 1][rr] = v.y;
            As[kq + 2][rr] = v.z; As[kq + 3][rr] = v.w;
        }
        // ---- stage W tile (64 n-rows x 32 k), transposed to k-major ----
        #pragma unroll
        for (int s = 0; s < 2; ++s) {
            int f = tid + (s << 8);
            int rr = f >> 3;
            int kq = (f & 7) << 2;
            int k = k0 + kq;
            int n = col0 + rr;
            float4 v = make_float4(0.f, 0.f, 0.f, 0.f);
            if (n < N) {
                const float* wp = W + (size_t)n * (size_t)ldw;
                if (k + 3 < kend) {
                    v = *(const float4*)(wp + k);
                } else {
                    if (k + 0 < kend) v.x = wp[k + 0];
                    if (k + 1 < kend) v.y = wp[k + 1];
                    if (k + 2 < kend) v.z = wp[k + 2];
                    if (k + 3 < kend) v.w = wp[k + 3];
                }
            }
            Ws[kq + 0][rr] = v.x; Ws[kq + 1][rr] = v.y;
            Ws[kq + 2][rr] = v.z; Ws[kq + 3][rr] = v.w;
        }
        __syncthreads();
        #pragma unroll
        for (int k = 0; k < 32; ++k) {
            float4 av = *(const float4*)&As[k][ty << 2];
            float4 bv = *(const float4*)&Ws[k][tx << 2];
            acc[0][0] = fmaf(av.x, bv.x, acc[0][0]);
            acc[0][1] = fmaf(av.x, bv.y, acc[0][1]);
            acc[0][2] = fmaf(av.x, bv.z, acc[0][2]);
            acc[0][3] = fmaf(av.x, bv.w, acc[0][3]);
            acc[1][0] = fmaf(av.y, bv.x, acc[1][0]);
            acc[1][1] = fmaf(av.y, bv.y, acc[1][1]);
            acc[1][2] = fmaf(av.y, bv.z, acc[1][2]);
            acc[1][3] = fmaf(av.y, bv.w, acc[1][3]);
            acc[2][0] = fmaf(av.z, bv.x, acc[2][0]);
            acc[2][1] = fmaf(av.z, bv.y, acc[2][1]);
            acc[2][2] = fmaf(av.z, bv.z, acc[2][2]);
            acc[2][3] = fmaf(av.z, bv.w, acc[2][3]);
            acc[3][0] = fmaf(av.w, bv.x, acc[3][0]);
            acc[3][1] = fmaf(av.w, bv.y, acc[3][1]);
            acc[3][2] = fmaf(av.w, bv.z, acc[3][2]);
            acc[3][3] = fmaf(av.w, bv.w, acc[3][3]);
        }
        __syncthreads();
    }

    #pragma unroll
    for (int i = 0; i < 4; ++i) {
        int rr = row0 + (ty << 2) + i;
        const float* bp = base + (size_t)rr * (size_t)ldc;
        float* cp = C + (size_t)rr * (size_t)ldc;
        #pragma unroll
        for (int j = 0; j < 4; ++j) {
            int cc = col0 + (tx << 2) + j;
            if (cc < N) {
                float v = acc[i][j];
                if (base) v += bp[cc];
                if (bias) v += bias[cc];
                if (relu) v = fmaxf(v, 0.f);
                cp[cc] = v;
            }
        }
    }
}

// ---------------------------------------------------------------------------
// Weight packing / prep kernels (run once per launch; ws is re-poisoned).
// ---------------------------------------------------------------------------
__global__ void pack_wcat_e(float* __restrict__ dst, const float* __restrict__ wih,
                            const float* __restrict__ whh) {
    int idx = blockIdx.x * 256 + threadIdx.x;
    if (idx >= G4 * 577) return;
    int n = idx / 577, k = idx % 577;
    dst[(size_t)n * 580 + k] = (k < 65) ? wih[n * 65 + k] : whh[(size_t)n * 512 + (k - 65)];
}
__global__ void pack_wcat_a(float* __restrict__ dst, const float* __restrict__ wih,
                            const float* __restrict__ whh) {
    int idx = blockIdx.x * 256 + threadIdx.x;
    if (idx >= G4 * 576) return;
    int n = idx / 576, k = idx % 576;
    dst[(size_t)n * 576 + k] = (k < 64) ? wih[(size_t)n * 584 + 520 + k]
                                        : whh[(size_t)n * 512 + (k - 64)];
}
__global__ void pack_wcat_t(float* __restrict__ dst, const float* __restrict__ wih,
                            const float* __restrict__ whh) {
    int idx = blockIdx.x * 256 + threadIdx.x;
    if (idx >= G4 * 577) return;
    int n = idx / 577, k = idx % 577;
    float v;
    if (k < 64)       v = wih[(size_t)n * 585 + 520 + k];
    else if (k == 64) v = wih[(size_t)n * 585 + 584];
    else              v = whh[(size_t)n * 512 + (k - 65)];
    dst[(size_t)n * 580 + k] = v;
}
__global__ void pack_sub520(float* __restrict__ dst, const float* __restrict__ src, int lds) {
    int idx = blockIdx.x * 256 + threadIdx.x;
    if (idx >= G4 * TDIM) return;
    int n = idx / TDIM, k = idx % TDIM;
    dst[(size_t)n * TDIM + k] = src[(size_t)n * lds + k];
}
__global__ void prep_misc(float* __restrict__ be, float* __restrict__ ba, float* __restrict__ bt,
                          float* __restrict__ wt,
                          const float* __restrict__ ebih, const float* __restrict__ ebhh,
                          const float* __restrict__ abih, const float* __restrict__ abhh,
                          const float* __restrict__ tbih, const float* __restrict__ tbhh,
                          const float* __restrict__ e2w) {
    int idx = blockIdx.x * 256 + threadIdx.x;
    if (idx < G4) {
        be[idx] = ebih[idx] + ebhh[idx];
        ba[idx] = abih[idx] + abhh[idx];
        bt[idx] = tbih[idx] + tbhh[idx];
    }
    if (idx < 512 * 64) {  // Wt_e2act[k][a] = e2act_W[a][k]
        int k = idx >> 6, a = idx & 63;
        wt[idx] = e2w[(size_t)a * 512 + k];
    }
}

// e_attrs -> relu(a2a) -> tcat[:, 0:8]
__global__ void attr_enc(float* __restrict__ tcat, const int* __restrict__ attr_cat,
                         const float* __restrict__ attr_num, const float* __restrict__ attr_emb,
                         const float* __restrict__ a2aW, const float* __restrict__ a2ab) {
    int idx = blockIdx.x * 256 + threadIdx.x;
    if (idx >= B * 8) return;
    int b = idx >> 3, o = idx & 7;
    const float* wr = a2aW + o * 17;
    const float* em = attr_emb + attr_cat[b] * 16;
    float s = a2ab[o];
    #pragma unroll
    for (int k = 0; k < 16; ++k) s = fmaf(em[k], wr[k], s);
    s = fmaf(attr_num[b], wr[16], s);
    tcat[(size_t)b * TDIM + o] = fmaxf(s, 0.f);
}

// Init encoder: Xcat_e step-0 input cols + zero h-cols, zero c, compute lens.
__global__ __launch_bounds__(256) void enc_init(
    float* __restrict__ xe, float* __restrict__ ce,
    const int* __restrict__ acts, const float* __restrict__ tsv,
    const float* __restrict__ act_emb, int* __restrict__ lens) {
    int b = blockIdx.x, tid = threadIdx.x;
    for (int j = tid; j < 577; j += 256) {
        float v;
        if (j < 64)       v = act_emb[acts[b * TT] * 64 + j];
        else if (j == 64) v = tsv[b * TT];
        else              v = 0.f;
        xe[(size_t)b * 580 + j] = v;
    }
    for (int j = tid; j < CF; j += 256) ce[(size_t)b * CF + j] = 0.f;
    if (tid < 64) {
        int v = acts[b * TT + tid];
        int m = v;
        #pragma unroll
        for (int off = 32; off; off >>= 1) m = max(m, __shfl_xor(m, off));
        unsigned long long mask = __ballot(v == m);
        if (tid == 0) lens[b] = __ffsll(mask) - 1;
    }
}

// Encoder LSTM cell. Writes h into Xcat_e[:,65:], captures cf row at t==len-1,
// and stages next step's input slice (embedding + ts).
__global__ __launch_bounds__(256) void cell_enc(
    const float* __restrict__ G, float* __restrict__ c,
    float* __restrict__ xe, float* __restrict__ tcat,
    const int* __restrict__ lens,
    const int* __restrict__ acts, const float* __restrict__ tsv,
    const float* __restrict__ act_emb, int t) {
    int idx = blockIdx.x * 256 + threadIdx.x;
    int b = idx >> 9, j = idx & 511;
    const float* g = G + (size_t)b * G4;
    float gi = g[j], gf = g[512 + j], gg = g[1024 + j], go = g[1536 + j];
    float cn = sigm(gf) * c[idx] + sigm(gi) * tanhf(gg);
    c[idx] = cn;
    float h = sigm(go) * tanhf(cn);
    xe[(size_t)b * 580 + 65 + j] = h;
    if (t == lens[b] - 1) tcat[(size_t)b * TDIM + 8 + j] = h;
    if (j < 65 && t < TT - 1) {
        float v = (j < 64) ? act_emb[acts[b * TT + t + 1] * 64 + j] : tsv[b * TT + t + 1];
        xe[(size_t)b * 580 + j] = v;
    }
}

__global__ void z_kernel(const float* __restrict__ m, const float* __restrict__ v,
                         const float* __restrict__ e, float* __restrict__ z) {
    int i = blockIdx.x * 256 + threadIdx.x;
    if (i < B * ZD) z[i] = fmaf(v[i], e[i], m[i]);
}

// attr heads: softmax(tc2(hid1)) and sigmoid(tn2(hid2))
__global__ __launch_bounds__(64) void attr_heads(
    const float* __restrict__ hid1, const float* __restrict__ hid2,
    const float* __restrict__ tc2W, const float* __restrict__ tc2b,
    const float* __restrict__ tn2W, const float* __restrict__ tn2b,
    float* __restrict__ out_cat, float* __restrict__ out_num) {
    __shared__ float h1[260], h2[260], sl[10];
    int b = blockIdx.x, tid = threadIdx.x;
    for (int k = tid; k < 260; k += 64) {
        h1[k] = hid1[(size_t)b * 260 + k];
        h2[k] = hid2[(size_t)b * 260 + k];
    }
    __syncthreads();
    if (tid < 10) {
        float l = tc2b[tid];
        const float* wr = tc2W + tid * 260;
        for (int k = 0; k < 260; ++k) l = fmaf(h1[k], wr[k], l);
        sl[tid] = l;
    }
    __syncthreads();
    if (tid < 10) {
        float m = sl[0];
        for (int i = 1; i < 10; ++i) m = fmaxf(m, sl[i]);
        float ssum = 0.f;
        for (int i = 0; i < 10; ++i) ssum += expf(sl[i] - m);
        out_cat[b * 10 + tid] = expf(sl[tid] - m) / ssum;
    }
    float p = 0.f;
    for (int k = tid; k < 260; k += 64) p = fmaf(h2[k], tn2W[k], p);
    #pragma unroll
    for (int off = 32; off; off >>= 1) p += __shfl_xor(p, off);
    if (tid == 0) out_num[b] = 1.f / (1.f + expf(-(p + tn2b[0])));
}

// Decoder init
__global__ __launch_bounds__(256) void dec_init(
    float* __restrict__ xa, float* __restrict__ xt,
    float* __restrict__ ca, float* __restrict__ ct,
    const float* __restrict__ act_emb) {
    int b = blockIdx.x, tid = threadIdx.x;
    for (int j = tid; j < 576; j += 256)
        xa[(size_t)b * 576 + j] = (j < 64) ? act_emb[63 * 64 + j] : 0.f;
    for (int j = tid; j < 577; j += 256)
        if (j >= 64) xt[(size_t)b * 580 + j] = 0.f;
    for (int j = tid; j < CF; j += 256) {
        ca[(size_t)b * CF + j] = 0.f;
        ct[(size_t)b * CF + j] = 0.f;
    }
}

// Fused: act-LSTM cell + logits + softmax + greedy argmax + embedding feedback.
__global__ __launch_bounds__(256) void cell_act_head(
    const float* __restrict__ G, float* __restrict__ c,
    float* __restrict__ xa,
    const float* __restrict__ Wt,   // [512][64] transposed e2act_W
    const float* __restrict__ e2b,
    const float* __restrict__ act_emb,
    float* __restrict__ out_acts,   // acts_rec base
    float* __restrict__ xt, int t) {
    __shared__ float hs[512];
    __shared__ float part[4][64];
    int b = blockIdx.x;
    const float* g = G + (size_t)b * G4;
    for (int j = threadIdx.x; j < 512; j += 256) {
        float gi = g[j], gf = g[512 + j], gg = g[1024 + j], go = g[1536 + j];
        float cn = sigm(gf) * c[(size_t)b * CF + j] + sigm(gi) * tanhf(gg);
        c[(size_t)b * CF + j] = cn;
        float h = sigm(go) * tanhf(cn);
        xa[(size_t)b * 576 + 64 + j] = h;
        hs[j] = h;
    }
    __syncthreads();
    int a = threadIdx.x & 63, s = threadIdx.x >> 6;
    int kk0 = s << 7;
    float p = 0.f;
    for (int k = 0; k < 128; ++k) p = fmaf(hs[kk0 + k], Wt[(kk0 + k) * 64 + a], p);
    part[s][a] = p;
    __syncthreads();
    if (threadIdx.x < 64) {
        float l = part[0][a] + part[1][a] + part[2][a] + part[3][a] + e2b[a];
        float m = l;
        #pragma unroll
        for (int off = 32; off; off >>= 1) m = fmaxf(m, __shfl_xor(m, off));
        float e = expf(l - m);
        float ssum = e;
        #pragma unroll
        for (int off = 32; off; off >>= 1) ssum += __shfl_xor(ssum, off);
        out_acts[((size_t)b * TT + t) * 64 + a] = e / ssum;
        unsigned long long mask = __ballot(l == m);
        int amax = __ffsll(mask) - 1;   // first occurrence of max (jnp.argmax)
        float av = act_emb[amax * 64 + a];
        xa[(size_t)b * 576 + a] = av;   // ae feedback (next step act-LSTM)
        xt[(size_t)b * 580 + a] = av;   // ae2 input (this step time-LSTM)
    }
}

// time-LSTM cell; writes h into Xcat_t[:,65:] and a packed aligned copy.
__global__ __launch_bounds__(256) void cell_t_kernel(
    const float* __restrict__ G, float* __restrict__ c,
    float* __restrict__ xt, float* __restrict__ htb) {
    int idx = blockIdx.x * 256 + threadIdx.x;
    int b = idx >> 9, j = idx & 511;
    const float* g = G + (size_t)b * G4;
    float gi = g[j], gf = g[512 + j], gg = g[1024 + j], go = g[1536 + j];
    float cn = sigm(gf) * c[idx] + sigm(gi) * tanhf(gg);
    c[idx] = cn;
    float h = sigm(go) * tanhf(cn);
    xt[(size_t)b * 580 + 65 + j] = h;
    htb[idx] = h;
}

// ts head stage 2: sum 4 split-K slices, +bias, relu, dot with ts2, emit.
__global__ __launch_bounds__(256) void ts2_head(
    const float* __restrict__ Gts,  // [4][512][256]
    const float* __restrict__ b1, const float* __restrict__ w2, const float* __restrict__ b2,
    float* __restrict__ out_ts, float* __restrict__ xt, int t) {
    __shared__ float red[16][17];
    int tid = threadIdx.x;
    int bb = tid >> 4, jj = tid & 15;
    int b = blockIdx.x * 16 + bb;
    float p = 0.f;
    #pragma unroll
    for (int i = 0; i < 16; ++i) {
        int j = (jj << 4) + i;
        size_t off = (size_t)b * 256 + j;
        float v = Gts[off] + Gts[131072 + off] + Gts[262144 + off] + Gts[393216 + off];
        v = fmaxf(v + b1[j], 0.f);
        p = fmaf(v, w2[j], p);
    }
    red[bb][jj] = p;
    __syncthreads();
    if (jj == 0) {
        float s = b2[0];
        #pragma unroll
        for (int i = 0; i < 16; ++i) s += red[bb][i];
        out_ts[b * TT + t] = s;
        xt[(size_t)b * 580 + 64] = s;  // tsc feedback
    }
}

// ---------------------------------------------------------------------------
extern "C" void kernel_launch(void* const* d_in, const int* in_sizes, int n_in,
                              void* d_out, int out_size, void* d_ws, size_t ws_size,
                              hipStream_t stream) {
    const int*   attr_cat = (const int*)  d_in[0];
    const float* attr_num = (const float*)d_in[1];
    const int*   acts     = (const int*)  d_in[2];
    const float* tsv      = (const float*)d_in[3];
    const float* eps      = (const float*)d_in[4];
    const float* attr_emb = (const float*)d_in[5];
    const float* a2a_W    = (const float*)d_in[6];
    const float* a2a_b    = (const float*)d_in[7];
    const float* act_emb  = (const float*)d_in[8];
    const float* eWih     = (const float*)d_in[9];
    const float* eWhh     = (const float*)d_in[10];
    const float* ebih     = (const float*)d_in[11];
    const float* ebhh     = (const float*)d_in[12];
    const float* mean_W   = (const float*)d_in[13];
    const float* mean_b   = (const float*)d_in[14];
    const float* var_W    = (const float*)d_in[15];
    const float* var_b    = (const float*)d_in[16];
    const float* z2t_W    = (const float*)d_in[17];
    const float* z2t_b    = (const float*)d_in[18];
    const float* tc1_W    = (const float*)d_in[19];
    const float* tc1_b    = (const float*)d_in[20];
    const float* tc2_W    = (const float*)d_in[21];
    const float* tc2_b    = (const float*)d_in[22];
    const float* tn1_W    = (const float*)d_in[23];
    const float* tn1_b    = (const float*)d_in[24];
    const float* tn2_W    = (const float*)d_in[25];
    const float* tn2_b    = (const float*)d_in[26];
    const float* aWih     = (const float*)d_in[27];
    const float* aWhh     = (const float*)d_in[28];
    const float* abih     = (const float*)d_in[29];
    const float* abhh     = (const float*)d_in[30];
    const float* tWih     = (const float*)d_in[31];
    const float* tWhh     = (const float*)d_in[32];
    const float* tbih     = (const float*)d_in[33];
    const float* tbhh     = (const float*)d_in[34];
    const float* e2act_W  = (const float*)d_in[35];
    const float* e2act_b  = (const float*)d_in[36];
    const float* ts1_W    = (const float*)d_in[37];
    const float* ts1_b    = (const float*)d_in[38];
    const float* ts2_W    = (const float*)d_in[39];
    const float* ts2_b    = (const float*)d_in[40];

    float* out = (float*)d_out;
    float* out_cat  = out;                 // [512,10]
    float* out_num  = out + 5120;          // [512,1]
    float* out_acts = out + 5632;          // [512,64,64]
    float* out_ts   = out + 2102784;       // [512,64]
    float* outm     = out + 2135552;       // [512,128]
    float* outv     = out + 2201088;       // [512,128]

    float* w = (float*)d_ws;
    auto alloc = [&](size_t n) { float* p = w; w += n; return p; };
    float* Wcat_e = alloc((size_t)G4 * 580);
    float* Wcat_a = alloc((size_t)G4 * 576);
    float* Wcat_t = alloc((size_t)G4 * 580);
    float* Wb_a   = alloc((size_t)G4 * TDIM);
    float* Wb_t   = alloc((size_t)G4 * TDIM);
    float* Wt_e2  = alloc(512 * 64);
    float* bias_e = alloc(G4);
    float* bias_a = alloc(G4);
    float* bias_t = alloc(G4);
    float* Xcat_e = alloc((size_t)B * 580);
    float* Xcat_a = alloc((size_t)B * 576);
    float* Xcat_t = alloc((size_t)B * 580);
    float* c_e    = alloc((size_t)B * CF);
    float* c_a    = alloc((size_t)B * CF);
    float* c_t    = alloc((size_t)B * CF);
    float* h_t_b  = alloc((size_t)B * CF);
    float* tcat   = alloc((size_t)B * TDIM);
    float* zbuf   = alloc((size_t)B * ZD);
    float* t_rec  = alloc((size_t)B * TDIM);
    float* hid1   = alloc((size_t)B * 260);
    float* hid2   = alloc((size_t)B * 260);
    float* base_a = alloc((size_t)B * G4);
    float* base_t = alloc((size_t)B * G4);
    float* Gbuf   = alloc((size_t)B * G4);
    float* G_ts   = alloc((size_t)4 * B * 256);
    int*   lens   = (int*)alloc(512);
    (void)ws_size; (void)in_sizes; (void)n_in; (void)out_size;

    // ---- prep (once per launch; ws is re-poisoned every call) ----
    pack_wcat_e<<<(G4 * 577 + 255) / 256, 256, 0, stream>>>(Wcat_e, eWih, eWhh);
    pack_wcat_a<<<(G4 * 576 + 255) / 256, 256, 0, stream>>>(Wcat_a, aWih, aWhh);
    pack_wcat_t<<<(G4 * 577 + 255) / 256, 256, 0, stream>>>(Wcat_t, tWih, tWhh);
    pack_sub520<<<(G4 * TDIM + 255) / 256, 256, 0, stream>>>(Wb_a, aWih, 584);
    pack_sub520<<<(G4 * TDIM + 255) / 256, 256, 0, stream>>>(Wb_t, tWih, 585);
    prep_misc<<<(512 * 64 + 255) / 256, 256, 0, stream>>>(bias_e, bias_a, bias_t, Wt_e2,
                                                          ebih, ebhh, abih, abhh, tbih, tbhh, e2act_W);
    attr_enc<<<(B * 8 + 255) / 256, 256, 0, stream>>>(tcat, attr_cat, attr_num, attr_emb, a2a_W, a2a_b);
    enc_init<<<B, 256, 0, stream>>>(Xcat_e, c_e, acts, tsv, act_emb, lens);

    // ---- encoder ----
    for (int t = 0; t < TT; ++t) {
        gemm_tn<<<dim3(32, 8, 1), 256, 0, stream>>>(Xcat_e, 580, Wcat_e, 580, G4, 577,
                                                    nullptr, bias_e, Gbuf, G4, 0);
        cell_enc<<<(B * CF) / 256, 256, 0, stream>>>(Gbuf, c_e, Xcat_e, tcat, lens,
                                                     acts, tsv, act_emb, t);
    }

    // ---- latent ----
    gemm_tn<<<dim3(2, 8, 1), 256, 0, stream>>>(tcat, TDIM, mean_W, TDIM, ZD, TDIM,
                                               nullptr, mean_b, outm, ZD, 0);
    gemm_tn<<<dim3(2, 8, 1), 256, 0, stream>>>(tcat, TDIM, var_W, TDIM, ZD, TDIM,
                                               nullptr, var_b, outv, ZD, 0);
    z_kernel<<<(B * ZD + 255) / 256, 256, 0, stream>>>(outm, outv, eps, zbuf);
    gemm_tn<<<dim3(9, 8, 1), 256, 0, stream>>>(zbuf, ZD, z2t_W, ZD, TDIM, ZD,
                                               nullptr, z2t_b, t_rec, TDIM, 1);
    gemm_tn<<<dim3(5, 8, 1), 256, 0, stream>>>(t_rec, TDIM, tc1_W, TDIM, 260, TDIM,
                                               nullptr, tc1_b, hid1, 260, 1);
    gemm_tn<<<dim3(5, 8, 1), 256, 0, stream>>>(t_rec, TDIM, tn1_W, TDIM, 260, TDIM,
                                               nullptr, tn1_b, hid2, 260, 1);
    attr_heads<<<B, 64, 0, stream>>>(hid1, hid2, tc2_W, tc2_b, tn2_W, tn2_b, out_cat, out_num);

    // decoder step-invariant input projections
    gemm_tn<<<dim3(32, 8, 1), 256, 0, stream>>>(t_rec, TDIM, Wb_a, TDIM, G4, TDIM,
                                                nullptr, bias_a, base_a, G4, 0);
    gemm_tn<<<dim3(32, 8, 1), 256, 0, stream>>>(t_rec, TDIM, Wb_t, TDIM, G4, TDIM,
                                                nullptr, bias_t, base_t, G4, 0);
    dec_init<<<B, 256, 0, stream>>>(Xcat_a, Xcat_t, c_a, c_t, act_emb);

    // ---- decoder ----
    for (int t = 0; t < TT; ++t) {
        gemm_tn<<<dim3(32, 8, 1), 256, 0, stream>>>(Xcat_a, 576, Wcat_a, 576, G4, 576,
                                                    base_a, nullptr, Gbuf, G4, 0);
        cell_act_head<<<B, 256, 0, stream>>>(Gbuf, c_a, Xcat_a, Wt_e2, e2act_b, act_emb,
                                             out_acts, Xcat_t, t);
        gemm_tn<<<dim3(32, 8, 1), 256, 0, stream>>>(Xcat_t, 580, Wcat_t, 580, G4, 577,
                                                    base_t, nullptr, Gbuf, G4, 0);
        cell_t_kernel<<<(B * CF) / 256, 256, 0, stream>>>(Gbuf, c_t, Xcat_t, h_t_b);
        gemm_tn<<<dim3(4, 8, 4), 256, 0, stream>>>(h_t_b, CF, ts1_W, CF, 256, CF,
                                                   nullptr, nullptr, G_ts, 256, 0);
        ts2_head<<<32, 256, 0, stream>>>(G_ts, ts1_b, ts2_W, ts2_b, out_ts, Xcat_t, t);
    }
}

// Round 3
// 8496.729 us; speedup vs baseline: 1.3838x; 1.3838x over previous
//
#include <hip/hip_runtime.h>
#include <math.h>

// ---------------------------------------------------------------------------
// VAE_14482629722138 — round 3: bf16 hi/lo MFMA GEMMs with fused LSTM cell.
// Identical to round 2 except __shared__ arrays explicitly 16B-aligned.
// B=512, T=64, CF=512, ZD=128, TDIM=520.
// ---------------------------------------------------------------------------

#define B 512
#define TT 64
#define CF 512
#define G4 2048
#define ZD 128
#define TDIM 520

typedef unsigned short u16;
typedef short bf16x8 __attribute__((ext_vector_type(8)));
typedef float f32x4 __attribute__((ext_vector_type(4)));

__device__ __forceinline__ float sigm(float x) { return 1.f / (1.f + expf(-x)); }
__device__ __forceinline__ u16 f2bf(float f) {
    unsigned u = __float_as_uint(f);
    u += 0x7fffu + ((u >> 16) & 1u);
    return (u16)(u >> 16);
}
__device__ __forceinline__ float bf2f(u16 s) { return __uint_as_float(((unsigned)s) << 16); }

// ---------------------------------------------------------------------------
// fp32 fallback GEMM: C[M,N] = A[M,K] @ W[N,K]^T (+bias)(relu). permW: W rows
// indexed through the gate-grouped permutation (for base_a/base_t).
// gridDim.z>1 -> split-K slices.
// ---------------------------------------------------------------------------
__global__ __launch_bounds__(256) void gemm_tn(
    const float* __restrict__ A, int lda,
    const float* __restrict__ W, int ldw,
    int N, int K,
    const float* __restrict__ bias,
    float* __restrict__ C, int ldc,
    int relu, int permW)
{
    __shared__ __align__(16) float As[32][68];
    __shared__ __align__(16) float Ws[32][68];
    const int tid = threadIdx.x;
    const int tx = tid & 15, ty = tid >> 4;
    const int row0 = blockIdx.y << 6;
    const int col0 = blockIdx.x << 6;

    int kbeg = 0, kend = K;
    if (gridDim.z > 1) {
        int kchunk = (K + gridDim.z - 1) / gridDim.z;
        kbeg = blockIdx.z * kchunk;
        kend = kbeg + kchunk; if (kend > K) kend = K;
        C += (size_t)blockIdx.z * (size_t)(gridDim.y << 6) * (size_t)ldc;
    }

    float acc[4][4] = {};

    for (int k0 = kbeg; k0 < kend; k0 += 32) {
        #pragma unroll
        for (int s = 0; s < 2; ++s) {
            int f = tid + (s << 8);
            int rr = f >> 3;
            int kq = (f & 7) << 2;
            int k = k0 + kq;
            float4 v = make_float4(0.f, 0.f, 0.f, 0.f);
            const float* ap = A + (size_t)(row0 + rr) * (size_t)lda;
            if (k + 3 < kend) v = *(const float4*)(ap + k);
            else {
                if (k + 0 < kend) v.x = ap[k + 0];
                if (k + 1 < kend) v.y = ap[k + 1];
                if (k + 2 < kend) v.z = ap[k + 2];
            }
            As[kq + 0][rr] = v.x; As[kq + 1][rr] = v.y;
            As[kq + 2][rr] = v.z; As[kq + 3][rr] = v.w;
        }
        #pragma unroll
        for (int s = 0; s < 2; ++s) {
            int f = tid + (s << 8);
            int rr = f >> 3;
            int kq = (f & 7) << 2;
            int k = k0 + kq;
            int n = col0 + rr;
            float4 v = make_float4(0.f, 0.f, 0.f, 0.f);
            if (n < N) {
                int nsrc = n;
                if (permW) {
                    int g = (n & 63) >> 4;
                    int cell = ((n >> 6) << 4) + (n & 15);
                    nsrc = (g << 9) + cell;
                }
                const float* wp = W + (size_t)nsrc * (size_t)ldw;
                if (k + 3 < kend) v = *(const float4*)(wp + k);
                else {
                    if (k + 0 < kend) v.x = wp[k + 0];
                    if (k + 1 < kend) v.y = wp[k + 1];
                    if (k + 2 < kend) v.z = wp[k + 2];
                }
            }
            Ws[kq + 0][rr] = v.x; Ws[kq + 1][rr] = v.y;
            Ws[kq + 2][rr] = v.z; Ws[kq + 3][rr] = v.w;
        }
        __syncthreads();
        #pragma unroll
        for (int k = 0; k < 32; ++k) {
            float4 av = *(const float4*)&As[k][ty << 2];
            float4 bv = *(const float4*)&Ws[k][tx << 2];
            acc[0][0] = fmaf(av.x, bv.x, acc[0][0]);
            acc[0][1] = fmaf(av.x, bv.y, acc[0][1]);
            acc[0][2] = fmaf(av.x, bv.z, acc[0][2]);
            acc[0][3] = fmaf(av.x, bv.w, acc[0][3]);
            acc[1][0] = fmaf(av.y, bv.x, acc[1][0]);
            acc[1][1] = fmaf(av.y, bv.y, acc[1][1]);
            acc[1][2] = fmaf(av.y, bv.z, acc[1][2]);
            acc[1][3] = fmaf(av.y, bv.w, acc[1][3]);
            acc[2][0] = fmaf(av.z, bv.x, acc[2][0]);
            acc[2][1] = fmaf(av.z, bv.y, acc[2][1]);
            acc[2][2] = fmaf(av.z, bv.z, acc[2][2]);
            acc[2][3] = fmaf(av.z, bv.w, acc[2][3]);
            acc[3][0] = fmaf(av.w, bv.x, acc[3][0]);
            acc[3][1] = fmaf(av.w, bv.y, acc[3][1]);
            acc[3][2] = fmaf(av.w, bv.z, acc[3][2]);
            acc[3][3] = fmaf(av.w, bv.w, acc[3][3]);
        }
        __syncthreads();
    }

    #pragma unroll
    for (int i = 0; i < 4; ++i) {
        int rr = row0 + (ty << 2) + i;
        float* cp = C + (size_t)rr * (size_t)ldc;
        #pragma unroll
        for (int j = 0; j < 4; ++j) {
            int cc = col0 + (tx << 2) + j;
            if (cc < N) {
                float v = acc[i][j];
                if (bias) v += bias[cc];
                if (relu) v = fmaxf(v, 0.f);
                cp[cc] = v;
            }
        }
    }
}

// ---------------------------------------------------------------------------
// MFMA GEMM + fused LSTM cell.
// C[512, 2048] = X @ Wpk^T, Wpk rows gate-grouped: n' = x*64 + gate*16 + (cell&15),
// block x owns cells x*16..x*16+15 (all 4 gates). 64x64 tile, 4 waves, each a
// 16x64 strip: acc[nt] = gate nt for cell = x*16 + (lane&15).
// hi/lo bf16 split: 3 MFMAs per fragment pair, fp32 accumulate.
// Epilogue: LSTM cell -> c update, h written as hi/lo bf16 into next X buffer.
// Encoder extras: tcat capture at t==len-1, x-column staging for t+1 (block x==0).
// ---------------------------------------------------------------------------
__global__ __launch_bounds__(256) void gemm_cell(
    const u16* __restrict__ Xhi, const u16* __restrict__ Xlo, int ldx,
    const u16* __restrict__ Whi, const u16* __restrict__ Wlo, int K,
    const float* __restrict__ base,    // [512][2048] permuted cols, or null
    const float* __restrict__ biaspk,  // [2048] permuted, or null
    float* __restrict__ c,             // [512][512]
    u16* __restrict__ Xnhi, u16* __restrict__ Xnlo, int ldxn, int hcol0,
    float* __restrict__ hfp,           // optional fp32 h out [512][512]
    float* __restrict__ tcat, const int* __restrict__ lens, int t,
    const int* __restrict__ acts, const float* __restrict__ tsv,
    const float* __restrict__ act_emb)
{
    __shared__ __align__(16) u16 As[2][64][40];
    __shared__ __align__(16) u16 Bs[2][64][40];
    const int tid = threadIdx.x;
    const int lane = tid & 63, ws = tid >> 6;
    const int fr = lane & 15;          // frag row / cell-in-group / D col
    const int quad = lane >> 4;
    const int ko = quad << 3;          // frag k offset
    const int row0 = blockIdx.y << 6;
    const int wrow0 = blockIdx.x << 6; // W packed row base

    const int srr = tid >> 2;          // staging row
    const int skq = (tid & 3) << 3;    // staging k offset (8 bf16)

    f32x4 acc[4] = {};

    for (int k0 = 0; k0 < K; k0 += 32) {
        const int xoff = (row0 + srr) * ldx + k0 + skq;
        const int woff = (wrow0 + srr) * K + k0 + skq;
        *(uint4*)&As[0][srr][skq] = *(const uint4*)(Xhi + xoff);
        *(uint4*)&As[1][srr][skq] = *(const uint4*)(Xlo + xoff);
        *(uint4*)&Bs[0][srr][skq] = *(const uint4*)(Whi + woff);
        *(uint4*)&Bs[1][srr][skq] = *(const uint4*)(Wlo + woff);
        __syncthreads();
        bf16x8 ah = *(const bf16x8*)&As[0][(ws << 4) + fr][ko];
        bf16x8 al = *(const bf16x8*)&As[1][(ws << 4) + fr][ko];
        #pragma unroll
        for (int nt = 0; nt < 4; ++nt) {
            bf16x8 bh = *(const bf16x8*)&Bs[0][(nt << 4) + fr][ko];
            bf16x8 bl = *(const bf16x8*)&Bs[1][(nt << 4) + fr][ko];
            acc[nt] = __builtin_amdgcn_mfma_f32_16x16x32_bf16(ah, bh, acc[nt], 0, 0, 0);
            acc[nt] = __builtin_amdgcn_mfma_f32_16x16x32_bf16(ah, bl, acc[nt], 0, 0, 0);
            acc[nt] = __builtin_amdgcn_mfma_f32_16x16x32_bf16(al, bh, acc[nt], 0, 0, 0);
        }
        __syncthreads();
    }

    // ---- epilogue: LSTM cell ----
    const int cell = (blockIdx.x << 4) + fr;
    const int rbase = row0 + (ws << 4) + (quad << 2);
    float bb[4];
    if (biaspk) {
        #pragma unroll
        for (int g = 0; g < 4; ++g) bb[g] = biaspk[(blockIdx.x << 6) + (g << 4) + fr];
    }
    #pragma unroll
    for (int r = 0; r < 4; ++r) {
        int b = rbase + r;
        float gi = acc[0][r], gf = acc[1][r], gg = acc[2][r], go = acc[3][r];
        if (base) {
            const float* bp = base + b * G4 + (blockIdx.x << 6) + fr;
            gi += bp[0]; gf += bp[16]; gg += bp[32]; go += bp[48];
        } else {
            gi += bb[0]; gf += bb[1]; gg += bb[2]; go += bb[3];
        }
        float cold = c[(b << 9) + cell];
        float cn = sigm(gf) * cold + sigm(gi) * tanhf(gg);
        c[(b << 9) + cell] = cn;
        float h = sigm(go) * tanhf(cn);
        u16 hh = f2bf(h);
        Xnhi[b * ldxn + hcol0 + cell] = hh;
        Xnlo[b * ldxn + hcol0 + cell] = f2bf(h - bf2f(hh));
        if (hfp) hfp[(b << 9) + cell] = h;
        if (lens && t == lens[b] - 1) tcat[b * TDIM + 8 + cell] = h;
    }

    // ---- encoder: stage x columns (emb + ts) for step t+1 ----
    if (acts && blockIdx.x == 0 && t < TT - 1) {
        for (int idx = tid; idx < 64 * 65; idx += 256) {
            int r = idx / 65, cc = idx - r * 65;
            int b = row0 + r;
            float v = (cc < 64) ? act_emb[acts[(b << 6) + t + 1] * 64 + cc]
                                : tsv[(b << 6) + t + 1];
            u16 hh = f2bf(v);
            Xnhi[b * ldxn + cc] = hh;
            Xnlo[b * ldxn + cc] = f2bf(v - bf2f(hh));
        }
    }
}

// ---------------------------------------------------------------------------
// Weight packing (gate-grouped, hi/lo bf16, zero-padded K).
// ---------------------------------------------------------------------------
__device__ __forceinline__ int perm_src(int np) {
    int g = (np & 63) >> 4;
    int cell = ((np >> 6) << 4) + (np & 15);
    return (g << 9) + cell;
}
__global__ void pack_we(u16* __restrict__ hi, u16* __restrict__ lo,
                        const float* __restrict__ wih, const float* __restrict__ whh) {
    int idx = blockIdx.x * 256 + threadIdx.x;
    if (idx >= G4 * 608) return;
    int np = idx / 608, k = idx - np * 608;
    int n = perm_src(np);
    float v = 0.f;
    if (k < 65) v = wih[n * 65 + k];
    else if (k < 577) v = whh[(n << 9) + k - 65];
    u16 h = f2bf(v); hi[idx] = h; lo[idx] = f2bf(v - bf2f(h));
}
__global__ void pack_wa(u16* __restrict__ hi, u16* __restrict__ lo,
                        const float* __restrict__ wih, const float* __restrict__ whh) {
    int idx = blockIdx.x * 256 + threadIdx.x;
    if (idx >= G4 * 576) return;
    int np = idx / 576, k = idx - np * 576;
    int n = perm_src(np);
    float v = (k < 64) ? wih[n * 584 + 520 + k] : whh[(n << 9) + k - 64];
    u16 h = f2bf(v); hi[idx] = h; lo[idx] = f2bf(v - bf2f(h));
}
__global__ void pack_wt(u16* __restrict__ hi, u16* __restrict__ lo,
                        const float* __restrict__ wih, const float* __restrict__ whh) {
    int idx = blockIdx.x * 256 + threadIdx.x;
    if (idx >= G4 * 608) return;
    int np = idx / 608, k = idx - np * 608;
    int n = perm_src(np);
    float v = 0.f;
    if (k < 64) v = wih[n * 585 + 520 + k];
    else if (k == 64) v = wih[n * 585 + 584];
    else if (k < 577) v = whh[(n << 9) + k - 65];
    u16 h = f2bf(v); hi[idx] = h; lo[idx] = f2bf(v - bf2f(h));
}

__global__ void prep_misc(float* __restrict__ be, float* __restrict__ ba, float* __restrict__ bt,
                          float* __restrict__ wt,
                          const float* __restrict__ ebih, const float* __restrict__ ebhh,
                          const float* __restrict__ abih, const float* __restrict__ abhh,
                          const float* __restrict__ tbih, const float* __restrict__ tbhh,
                          const float* __restrict__ e2w) {
    int idx = blockIdx.x * 256 + threadIdx.x;
    if (idx < G4) {
        int n = perm_src(idx);
        be[idx] = ebih[n] + ebhh[n];
        ba[idx] = abih[n] + abhh[n];
        bt[idx] = tbih[n] + tbhh[n];
    }
    if (idx < 512 * 64) {  // WtT[k][a] = e2act_W[a][k]
        int k = idx >> 6, a = idx & 63;
        wt[idx] = e2w[(a << 9) + k];
    }
}

__global__ void attr_enc(float* __restrict__ tcat, const int* __restrict__ attr_cat,
                         const float* __restrict__ attr_num, const float* __restrict__ attr_emb,
                         const float* __restrict__ a2aW, const float* __restrict__ a2ab) {
    int idx = blockIdx.x * 256 + threadIdx.x;
    if (idx >= B * 8) return;
    int b = idx >> 3, o = idx & 7;
    const float* wr = a2aW + o * 17;
    const float* em = attr_emb + attr_cat[b] * 16;
    float s = a2ab[o];
    #pragma unroll
    for (int k = 0; k < 16; ++k) s = fmaf(em[k], wr[k], s);
    s = fmaf(attr_num[b], wr[16], s);
    tcat[b * TDIM + o] = fmaxf(s, 0.f);
}

__global__ __launch_bounds__(256) void enc_init(
    u16* __restrict__ xh, u16* __restrict__ xl, float* __restrict__ ce,
    const int* __restrict__ acts, const float* __restrict__ tsv,
    const float* __restrict__ act_emb, int* __restrict__ lens) {
    int b = blockIdx.x, tid = threadIdx.x;
    for (int j = tid; j < 608; j += 256) {
        float v = 0.f;
        if (j < 64) v = act_emb[acts[b << 6] * 64 + j];
        else if (j == 64) v = tsv[b << 6];
        u16 hh = f2bf(v);
        xh[b * 608 + j] = hh; xl[b * 608 + j] = f2bf(v - bf2f(hh));
        if (j >= 577) { xh[512 * 608 + b * 608 + j] = 0; xl[512 * 608 + b * 608 + j] = 0; }
    }
    for (int j = tid; j < CF; j += 256) ce[(b << 9) + j] = 0.f;
    if (tid < 64) {
        int v = acts[(b << 6) + tid];
        int m = v;
        #pragma unroll
        for (int off = 32; off; off >>= 1) m = max(m, __shfl_xor(m, off));
        unsigned long long mask = __ballot(v == m);
        if (tid == 0) lens[b] = __ffsll(mask) - 1;
    }
}

__global__ void z_kernel(const float* __restrict__ m, const float* __restrict__ v,
                         const float* __restrict__ e, float* __restrict__ z) {
    int i = blockIdx.x * 256 + threadIdx.x;
    if (i < B * ZD) z[i] = fmaf(v[i], e[i], m[i]);
}

__global__ __launch_bounds__(64) void attr_heads(
    const float* __restrict__ hid1, const float* __restrict__ hid2,
    const float* __restrict__ tc2W, const float* __restrict__ tc2b,
    const float* __restrict__ tn2W, const float* __restrict__ tn2b,
    float* __restrict__ out_cat, float* __restrict__ out_num) {
    __shared__ __align__(16) float h1[260], h2[260], sl[10];
    int b = blockIdx.x, tid = threadIdx.x;
    for (int k = tid; k < 260; k += 64) {
        h1[k] = hid1[b * 260 + k];
        h2[k] = hid2[b * 260 + k];
    }
    __syncthreads();
    if (tid < 10) {
        float l = tc2b[tid];
        const float* wr = tc2W + tid * 260;
        for (int k = 0; k < 260; ++k) l = fmaf(h1[k], wr[k], l);
        sl[tid] = l;
    }
    __syncthreads();
    if (tid < 10) {
        float m = sl[0];
        for (int i = 1; i < 10; ++i) m = fmaxf(m, sl[i]);
        float ssum = 0.f;
        for (int i = 0; i < 10; ++i) ssum += expf(sl[i] - m);
        out_cat[b * 10 + tid] = expf(sl[tid] - m) / ssum;
    }
    float p = 0.f;
    for (int k = tid; k < 260; k += 64) p = fmaf(h2[k], tn2W[k], p);
    #pragma unroll
    for (int off = 32; off; off >>= 1) p += __shfl_xor(p, off);
    if (tid == 0) out_num[b] = 1.f / (1.f + expf(-(p + tn2b[0])));
}

__global__ __launch_bounds__(256) void dec_init(
    u16* __restrict__ xah, u16* __restrict__ xal,
    u16* __restrict__ xth, u16* __restrict__ xtl,
    float* __restrict__ ca, float* __restrict__ ct,
    const float* __restrict__ act_emb) {
    int b = blockIdx.x, tid = threadIdx.x;
    for (int j = tid; j < 576; j += 256) {
        float v = (j < 64) ? act_emb[63 * 64 + j] : 0.f;
        u16 hh = f2bf(v);
        xah[b * 576 + j] = hh; xal[b * 576 + j] = f2bf(v - bf2f(hh));
    }
    for (int j = tid; j < 608; j += 256) {
        if (j >= 64) { xth[b * 608 + j] = 0; xtl[b * 608 + j] = 0; }
        if (j >= 577) { xth[512 * 608 + b * 608 + j] = 0; xtl[512 * 608 + b * 608 + j] = 0; }
    }
    for (int j = tid; j < CF; j += 256) { ca[(b << 9) + j] = 0.f; ct[(b << 9) + j] = 0.f; }
}

// logits + softmax + greedy argmax + embedding feedback (h from hi/lo X).
__global__ __launch_bounds__(64) void act_head(
    const u16* __restrict__ Xanh, const u16* __restrict__ Xanl,
    const float* __restrict__ WtT, const float* __restrict__ e2b,
    const float* __restrict__ act_emb, float* __restrict__ out_acts,
    u16* __restrict__ aeh, u16* __restrict__ ael,
    u16* __restrict__ xth, u16* __restrict__ xtl, int t) {
    __shared__ __align__(16) float hs[512];
    int b = blockIdx.x, a = threadIdx.x;
    for (int k = a; k < 512; k += 64)
        hs[k] = bf2f(Xanh[b * 576 + 64 + k]) + bf2f(Xanl[b * 576 + 64 + k]);
    __syncthreads();
    float l = e2b[a];
    #pragma unroll 8
    for (int k = 0; k < 512; ++k) l = fmaf(hs[k], WtT[(k << 6) + a], l);
    float m = l;
    #pragma unroll
    for (int off = 32; off; off >>= 1) m = fmaxf(m, __shfl_xor(m, off));
    float e = expf(l - m), s = e;
    #pragma unroll
    for (int off = 32; off; off >>= 1) s += __shfl_xor(s, off);
    out_acts[(((b << 6) + t) << 6) + a] = e / s;
    unsigned long long mask = __ballot(l == m);
    int amax = __ffsll(mask) - 1;
    float av = act_emb[(amax << 6) + a];
    u16 hh = f2bf(av), hl = f2bf(av - bf2f(hh));
    aeh[b * 576 + a] = hh; ael[b * 576 + a] = hl;
    xth[b * 608 + a] = hh; xtl[b * 608 + a] = hl;
}

// ts head stage 2: sum 8 split-K slices, relu, dot ts2, feedback.
__global__ __launch_bounds__(256) void ts2_head(
    const float* __restrict__ Gts, const float* __restrict__ b1,
    const float* __restrict__ w2, const float* __restrict__ b2,
    float* __restrict__ out_ts, u16* __restrict__ xth, u16* __restrict__ xtl, int t) {
    __shared__ __align__(16) float red[16][17];
    int tid = threadIdx.x, bb = tid >> 4, jj = tid & 15;
    int b = blockIdx.x * 16 + bb;
    float p = 0.f;
    for (int i = 0; i < 16; ++i) {
        int j = (jj << 4) + i;
        int off = (b << 8) + j;
        float v = 0.f;
        #pragma unroll
        for (int s = 0; s < 8; ++s) v += Gts[s * 131072 + off];
        v = fmaxf(v + b1[j], 0.f);
        p = fmaf(v, w2[j], p);
    }
    red[bb][jj] = p;
    __syncthreads();
    if (jj == 0) {
        float s = b2[0];
        #pragma unroll
        for (int i = 0; i < 16; ++i) s += red[bb][i];
        out_ts[(b << 6) + t] = s;
        u16 hh = f2bf(s);
        xth[b * 608 + 64] = hh; xtl[b * 608 + 64] = f2bf(s - bf2f(hh));
    }
}

// ---------------------------------------------------------------------------
extern "C" void kernel_launch(void* const* d_in, const int* in_sizes, int n_in,
                              void* d_out, int out_size, void* d_ws, size_t ws_size,
                              hipStream_t stream) {
    const int*   attr_cat = (const int*)  d_in[0];
    const float* attr_num = (const float*)d_in[1];
    const int*   acts     = (const int*)  d_in[2];
    const float* tsv      = (const float*)d_in[3];
    const float* eps      = (const float*)d_in[4];
    const float* attr_emb = (const float*)d_in[5];
    const float* a2a_W    = (const float*)d_in[6];
    const float* a2a_b    = (const float*)d_in[7];
    const float* act_emb  = (const float*)d_in[8];
    const float* eWih     = (const float*)d_in[9];
    const float* eWhh     = (const float*)d_in[10];
    const float* ebih     = (const float*)d_in[11];
    const float* ebhh     = (const float*)d_in[12];
    const float* mean_W   = (const float*)d_in[13];
    const float* mean_b   = (const float*)d_in[14];
    const float* var_W    = (const float*)d_in[15];
    const float* var_b    = (const float*)d_in[16];
    const float* z2t_W    = (const float*)d_in[17];
    const float* z2t_b    = (const float*)d_in[18];
    const float* tc1_W    = (const float*)d_in[19];
    const float* tc1_b    = (const float*)d_in[20];
    const float* tc2_W    = (const float*)d_in[21];
    const float* tc2_b    = (const float*)d_in[22];
    const float* tn1_W    = (const float*)d_in[23];
    const float* tn1_b    = (const float*)d_in[24];
    const float* tn2_W    = (const float*)d_in[25];
    const float* tn2_b    = (const float*)d_in[26];
    const float* aWih     = (const float*)d_in[27];
    const float* aWhh     = (const float*)d_in[28];
    const float* abih     = (const float*)d_in[29];
    const float* abhh     = (const float*)d_in[30];
    const float* tWih     = (const float*)d_in[31];
    const float* tWhh     = (const float*)d_in[32];
    const float* tbih     = (const float*)d_in[33];
    const float* tbhh     = (const float*)d_in[34];
    const float* e2act_W  = (const float*)d_in[35];
    const float* e2act_b  = (const float*)d_in[36];
    const float* ts1_W    = (const float*)d_in[37];
    const float* ts1_b    = (const float*)d_in[38];
    const float* ts2_W    = (const float*)d_in[39];
    const float* ts2_b    = (const float*)d_in[40];

    float* out = (float*)d_out;
    float* out_cat  = out;
    float* out_num  = out + 5120;
    float* out_acts = out + 5632;
    float* out_ts   = out + 2102784;
    float* outm     = out + 2135552;
    float* outv     = out + 2201088;

    char* w = (char*)d_ws;
    auto alloc = [&](size_t bytes) { char* p = w; w += (bytes + 255) & ~(size_t)255; return p; };
    // --- persistent region ---
    u16*   Wt_hi  = (u16*)alloc((size_t)G4 * 608 * 2);
    u16*   Wt_lo  = (u16*)alloc((size_t)G4 * 608 * 2);
    float* WtT    = (float*)alloc(512 * 64 * 4);
    float* bias_e = (float*)alloc(G4 * 4);
    float* bias_a = (float*)alloc(G4 * 4);
    float* bias_t = (float*)alloc(G4 * 4);
    float* base_a = (float*)alloc((size_t)B * G4 * 4);
    float* base_t = (float*)alloc((size_t)B * G4 * 4);
    u16*   Xa_hi  = (u16*)alloc((size_t)2 * B * 576 * 2);
    u16*   Xa_lo  = (u16*)alloc((size_t)2 * B * 576 * 2);
    u16*   Xt_hi  = (u16*)alloc((size_t)2 * B * 608 * 2);
    u16*   Xt_lo  = (u16*)alloc((size_t)2 * B * 608 * 2);
    float* c_a    = (float*)alloc((size_t)B * CF * 4);
    float* c_t    = (float*)alloc((size_t)B * CF * 4);
    float* htb    = (float*)alloc((size_t)B * CF * 4);
    float* tcat   = (float*)alloc((size_t)B * TDIM * 4);
    float* t_rec  = (float*)alloc((size_t)B * TDIM * 4);
    float* zbuf   = (float*)alloc((size_t)B * ZD * 4);
    float* hid1   = (float*)alloc((size_t)B * 260 * 4);
    float* hid2   = (float*)alloc((size_t)B * 260 * 4);
    int*   lens   = (int*)alloc(512 * 4);
    // --- phase overlay: encoder {We,Xe,c_e} / decoder {Wa,G_ts} ---
    char* phase = w;
    u16*   We_hi  = (u16*)(phase);
    u16*   We_lo  = (u16*)(phase + (size_t)G4 * 608 * 2);
    u16*   Xe_hi  = (u16*)(phase + (size_t)2 * G4 * 608 * 2);
    u16*   Xe_lo  = (u16*)(phase + (size_t)2 * G4 * 608 * 2 + (size_t)2 * B * 608 * 2);
    float* c_e    = (float*)(phase + (size_t)2 * G4 * 608 * 2 + (size_t)4 * B * 608 * 2);
    u16*   Wa_hi  = (u16*)(phase);
    u16*   Wa_lo  = (u16*)(phase + (size_t)G4 * 576 * 2);
    float* G_ts   = (float*)(phase + (size_t)2 * G4 * 576 * 2);
    (void)ws_size; (void)in_sizes; (void)n_in; (void)out_size;

    // ---- prep ----
    pack_we<<<(G4 * 608 + 255) / 256, 256, 0, stream>>>(We_hi, We_lo, eWih, eWhh);
    pack_wt<<<(G4 * 608 + 255) / 256, 256, 0, stream>>>(Wt_hi, Wt_lo, tWih, tWhh);
    prep_misc<<<128, 256, 0, stream>>>(bias_e, bias_a, bias_t, WtT,
                                       ebih, ebhh, abih, abhh, tbih, tbhh, e2act_W);
    attr_enc<<<(B * 8 + 255) / 256, 256, 0, stream>>>(tcat, attr_cat, attr_num, attr_emb, a2a_W, a2a_b);
    enc_init<<<B, 256, 0, stream>>>(Xe_hi, Xe_lo, c_e, acts, tsv, act_emb, lens);

    // ---- encoder ----
    for (int t = 0; t < TT; ++t) {
        const u16* xh = Xe_hi + (size_t)(t & 1) * B * 608;
        const u16* xl = Xe_lo + (size_t)(t & 1) * B * 608;
        u16* xnh = Xe_hi + (size_t)((t + 1) & 1) * B * 608;
        u16* xnl = Xe_lo + (size_t)((t + 1) & 1) * B * 608;
        gemm_cell<<<dim3(32, 8), 256, 0, stream>>>(
            xh, xl, 608, We_hi, We_lo, 608, nullptr, bias_e, c_e,
            xnh, xnl, 608, 65, nullptr, tcat, lens, t, acts, tsv, act_emb);
    }

    // ---- latent ----
    gemm_tn<<<dim3(2, 8, 1), 256, 0, stream>>>(tcat, TDIM, mean_W, TDIM, ZD, TDIM,
                                               mean_b, outm, ZD, 0, 0);
    gemm_tn<<<dim3(2, 8, 1), 256, 0, stream>>>(tcat, TDIM, var_W, TDIM, ZD, TDIM,
                                               var_b, outv, ZD, 0, 0);
    z_kernel<<<(B * ZD + 255) / 256, 256, 0, stream>>>(outm, outv, eps, zbuf);
    gemm_tn<<<dim3(9, 8, 1), 256, 0, stream>>>(zbuf, ZD, z2t_W, ZD, TDIM, ZD,
                                               z2t_b, t_rec, TDIM, 1, 0);
    gemm_tn<<<dim3(5, 8, 1), 256, 0, stream>>>(t_rec, TDIM, tc1_W, TDIM, 260, TDIM,
                                               tc1_b, hid1, 260, 1, 0);
    gemm_tn<<<dim3(5, 8, 1), 256, 0, stream>>>(t_rec, TDIM, tn1_W, TDIM, 260, TDIM,
                                               tn1_b, hid2, 260, 1, 0);
    attr_heads<<<B, 64, 0, stream>>>(hid1, hid2, tc2_W, tc2_b, tn2_W, tn2_b, out_cat, out_num);

    // ---- decoder prep (Wa packs AFTER encoder: overlays We region) ----
    pack_wa<<<(G4 * 576 + 255) / 256, 256, 0, stream>>>(Wa_hi, Wa_lo, aWih, aWhh);
    gemm_tn<<<dim3(32, 8, 1), 256, 0, stream>>>(t_rec, TDIM, aWih, 584, G4, TDIM,
                                                bias_a, base_a, G4, 0, 1);
    gemm_tn<<<dim3(32, 8, 1), 256, 0, stream>>>(t_rec, TDIM, tWih, 585, G4, TDIM,
                                                bias_t, base_t, G4, 0, 1);
    dec_init<<<B, 256, 0, stream>>>(Xa_hi, Xa_lo, Xt_hi, Xt_lo, c_a, c_t, act_emb);

    // ---- decoder ----
    for (int t = 0; t < TT; ++t) {
        u16* xah = Xa_hi + (size_t)(t & 1) * B * 576;
        u16* xal = Xa_lo + (size_t)(t & 1) * B * 576;
        u16* xanh = Xa_hi + (size_t)((t + 1) & 1) * B * 576;
        u16* xanl = Xa_lo + (size_t)((t + 1) & 1) * B * 576;
        u16* xth = Xt_hi + (size_t)(t & 1) * B * 608;
        u16* xtl = Xt_lo + (size_t)(t & 1) * B * 608;
        u16* xtnh = Xt_hi + (size_t)((t + 1) & 1) * B * 608;
        u16* xtnl = Xt_lo + (size_t)((t + 1) & 1) * B * 608;

        gemm_cell<<<dim3(32, 8), 256, 0, stream>>>(
            xah, xal, 576, Wa_hi, Wa_lo, 576, base_a, nullptr, c_a,
            xanh, xanl, 576, 64, nullptr, nullptr, nullptr, t, nullptr, nullptr, nullptr);
        act_head<<<B, 64, 0, stream>>>(xanh, xanl, WtT, e2act_b, act_emb, out_acts,
                                       xanh, xanl, xth, xtl, t);
        gemm_cell<<<dim3(32, 8), 256, 0, stream>>>(
            xth, xtl, 608, Wt_hi, Wt_lo, 608, base_t, nullptr, c_t,
            xtnh, xtnl, 608, 65, htb, nullptr, nullptr, t, nullptr, nullptr, nullptr);
        gemm_tn<<<dim3(4, 8, 8), 256, 0, stream>>>(htb, CF, ts1_W, CF, 256, CF,
                                                   nullptr, G_ts, 256, 0, 0);
        ts2_head<<<32, 256, 0, stream>>>(G_ts, ts1_b, ts2_W, ts2_b, out_ts, xtnh, xtnl, t);
    }
}